// Round 4
// baseline (1219.470 us; speedup 1.0000x reference)
//
#include <hip/hip_runtime.h>
#include <stdint.h>
#include <math.h>
#include <limits.h>

#define EPS 1e-5f

typedef __attribute__((ext_vector_type(4))) __bf16 bf16x4;
typedef __attribute__((ext_vector_type(8))) __bf16 bf16x8;
typedef __attribute__((ext_vector_type(16))) float f32x16;

// ---------------------------------------------------------------------------
// conv1 weight prep: w [96,3,11,11] fp32 -> hi/lo bf16 in layout
// [otile(3)][krow(33)][o(32)][kw(16)]  (kw 11..15 zero-padded)
// ---------------------------------------------------------------------------
__global__ __launch_bounds__(256) void conv1_wprep(
    const float* __restrict__ w, __bf16* __restrict__ wth, __bf16* __restrict__ wtl)
{
    int idx = blockIdx.x * 256 + threadIdx.x;
    if (idx >= 96 * 33 * 16) return;
    int kw = idx & 15;
    int kr = (idx >> 4) % 33;
    int og = idx / (16 * 33);
    int ot = og >> 5, o = og & 31;
    float v = 0.f;
    if (kw < 11) v = w[og * 363 + kr * 11 + kw];
    __bf16 h = (__bf16)v;
    size_t dst = ((size_t)(ot * 33 + kr) * 32 + o) * 16 + kw;
    wth[dst] = h;
    wtl[dst] = (__bf16)(v - (float)h);
}

// ---------------------------------------------------------------------------
// conv1 via MFMA (bf16 hi/lo 3-pass): grid (55 oy, 128 b), block 384 = 6 waves
// ---------------------------------------------------------------------------
__global__ __launch_bounds__(384) void conv1_mfma(
    const float* __restrict__ x, const __bf16* __restrict__ wth,
    const __bf16* __restrict__ wtl, float* __restrict__ out)
{
    const int oy = blockIdx.x;
    const int b  = blockIdx.y;
    __shared__ __bf16 ldsbuf[2 * 33 * 264 + 8];
    __bf16* ldsH = ldsbuf;
    __bf16* ldsL = ldsbuf + 33 * 264;

    const float* xb = x + (size_t)b * 3 * 224 * 224;
    for (int idx = threadIdx.x; idx < 33 * 33; idx += 384) {
        int r = idx / 33, q = idx % 33;
        int c = r / 11, kh = r % 11;
        int iy = 4 * oy + kh - 2;
        const float* src = xb + ((size_t)c * 224 + iy) * 224;
        bf16x8 hv, lv;
        #pragma unroll
        for (int j = 0; j < 8; ++j) {
            int ix = q * 8 + j - 2;
            float v = 0.f;
            if ((unsigned)iy < 224u && (unsigned)ix < 224u) v = src[ix];
            __bf16 h = (__bf16)v;
            hv[j] = h;
            lv[j] = (__bf16)(v - (float)h);
        }
        *(bf16x8*)(ldsH + r * 264 + q * 8) = hv;
        *(bf16x8*)(ldsL + r * 264 + q * 8) = lv;
    }
    __syncthreads();

    const int wv = threadIdx.x >> 6;
    const int l  = threadIdx.x & 63;
    const int ot = wv >> 1, xt = wv & 1;
    const int col = l & 31, kg = l >> 5;

    f32x16 acc = {};
    const int bpos = 4 * (xt * 32 + col) + 8 * kg;
    const int wofs = col * 16 + kg * 8;

    for (int kr = 0; kr < 33; ++kr) {
        const size_t wko = (size_t)(ot * 33 + kr) * 512 + wofs;
        bf16x8 ah = *(const bf16x8*)(wth + wko);
        bf16x8 al = *(const bf16x8*)(wtl + wko);
        const __bf16* rH = ldsH + kr * 264 + bpos;
        const __bf16* rL = ldsL + kr * 264 + bpos;
        bf16x4 bh0 = *(const bf16x4*)rH;
        bf16x4 bh1 = *(const bf16x4*)(rH + 4);
        bf16x4 bl0 = *(const bf16x4*)rL;
        bf16x4 bl1 = *(const bf16x4*)(rL + 4);
        bf16x8 bh = __builtin_shufflevector(bh0, bh1, 0, 1, 2, 3, 4, 5, 6, 7);
        bf16x8 bl = __builtin_shufflevector(bl0, bl1, 0, 1, 2, 3, 4, 5, 6, 7);
        acc = __builtin_amdgcn_mfma_f32_32x32x16_bf16(ah, bh, acc, 0, 0, 0);
        acc = __builtin_amdgcn_mfma_f32_32x32x16_bf16(ah, bl, acc, 0, 0, 0);
        acc = __builtin_amdgcn_mfma_f32_32x32x16_bf16(al, bh, acc, 0, 0, 0);
    }

    const int ox = xt * 32 + col;
    if (ox < 55) {
        float* ob = out + ((size_t)(b * 96 + ot * 32) * 55 + oy) * 55 + ox;
        #pragma unroll
        for (int i = 0; i < 16; ++i) {
            int row = (i & 3) + 8 * (i >> 2) + 4 * kg;
            ob[(size_t)row * 55 * 55] = acc[i];
        }
    }
}

// ---------------------------------------------------------------------------
// stage1: A [128,96,55,55] -> maxpool3x3s2 -> bn1 -> sign -> pack pad2
// out PB1 [128,3,31,31] words
// ---------------------------------------------------------------------------
__global__ __launch_bounds__(256) void poolpack1(
    const float* __restrict__ A, uint32_t* __restrict__ pout,
    const float* __restrict__ bnp)
{
    int idx = blockIdx.x * 256 + threadIdx.x;
    if (idx >= 128 * 3 * 31 * 31) return;
    int xp = idx % 31, t = idx / 31;
    int yp = t % 31; t /= 31;
    int cw = t % 3; int b = t / 3;
    uint32_t word = 0xFFFFFFFFu;
    if (yp >= 2 && yp <= 28 && xp >= 2 && xp <= 28) {
        int py = yp - 2, px = xp - 2;
        word = 0u;
        #pragma unroll 4
        for (int j = 0; j < 32; ++j) {
            int c = cw * 32 + j;
            const float* base = A + ((size_t)(b * 96 + c) * 55 + 2 * py) * 55 + 2 * px;
            float mx = base[0];
            mx = fmaxf(mx, base[1]);   mx = fmaxf(mx, base[2]);
            mx = fmaxf(mx, base[55]);  mx = fmaxf(mx, base[56]);  mx = fmaxf(mx, base[57]);
            mx = fmaxf(mx, base[110]); mx = fmaxf(mx, base[111]); mx = fmaxf(mx, base[112]);
            float scale = bnp[c] / sqrtf(bnp[288 + c] + EPS);
            float bnv = (mx - bnp[192 + c]) * scale + bnp[96 + c];
            if (bnv < 0.f) word |= 1u << j;
        }
    }
    pout[idx] = word;
}

// pack conv weights [O,C,KH,KW] -> [O, C/32, KH*KW] u32 (bit j = channel cw*32+j)
__global__ __launch_bounds__(256) void packw_kernel(
    const float* __restrict__ w, uint32_t* __restrict__ out,
    int C, int KK, int total)
{
    int idx = blockIdx.x * 256 + threadIdx.x;
    if (idx >= total) return;
    int kk = idx % KK, t = idx / KK;
    int cw = t % (C / 32); int o = t / (C / 32);
    const float* base = w + ((size_t)o * C + cw * 32) * KK + kk;
    uint32_t word = 0;
    #pragma unroll
    for (int j = 0; j < 32; ++j)
        word |= (base[(size_t)j * KK] < 0.f) ? (1u << j) : 0u;
    out[idx] = word;
}

// ---------------------------------------------------------------------------
// binconv2 + maxpool + bn2 + sign + pack pad1, fused.
// in PB1 [b][3][31][31], w [256][75], out PB2 [b][8][15][15]
// grid (15 yp, 2 ot, 128 b), block 256. thread = (o_local 128, xhalf 2)
// ---------------------------------------------------------------------------
__global__ __launch_bounds__(256) void binconv2_pool(
    const uint32_t* __restrict__ pa, const uint32_t* __restrict__ pw,
    uint32_t* __restrict__ pout, const float* __restrict__ bnp)
{
    const int yp = blockIdx.x, ot = blockIdx.y, b = blockIdx.z;
    __shared__ uint32_t wl[75 * 129];
    __shared__ uint32_t al[651 + 24];
    if (yp == 0 || yp == 14) {
        for (int i = threadIdx.x; i < 60; i += 256) {
            int cw4 = i / 15, xp = i % 15;
            pout[((size_t)(b * 8 + ot * 4 + cw4) * 15 + yp) * 15 + xp] = 0xFFFFFFFFu;
        }
        return;
    }
    const int py = yp - 1;
    const uint32_t* pwb = pw + (size_t)(ot * 128) * 75;
    for (int idx = threadIdx.x; idx < 128 * 75; idx += 256) {
        int o = idx / 75, k = idx % 75;
        wl[k * 129 + o] = pwb[idx];
    }
    const uint32_t* pab = pa + (size_t)b * 3 * 961;
    for (int idx = threadIdx.x; idx < 651; idx += 256) {
        int cw = idx / 217, rr = (idx / 31) % 7, xp = idx % 31;
        al[idx] = pab[(size_t)cw * 961 + (2 * py + rr) * 31 + xp];
    }
    __syncthreads();

    const int ol = threadIdx.x & 127;
    const int xh = threadIdx.x >> 7;
    const int xs = xh * 14;
    int smin[7] = {INT_MAX, INT_MAX, INT_MAX, INT_MAX, INT_MAX, INT_MAX, INT_MAX};

    for (int r = 0; r < 3; ++r) {
        int s[15] = {0,0,0,0,0,0,0,0,0,0,0,0,0,0,0};
        #pragma unroll
        for (int cw = 0; cw < 3; ++cw)
            #pragma unroll
            for (int kh = 0; kh < 5; ++kh) {
                uint32_t aw[19];
                #pragma unroll
                for (int j = 0; j < 19; ++j)
                    aw[j] = al[cw * 217 + (r + kh) * 31 + xs + j];
                #pragma unroll
                for (int kw = 0; kw < 5; ++kw) {
                    uint32_t wk = wl[(cw * 25 + kh * 5 + kw) * 129 + ol];
                    #pragma unroll
                    for (int x = 0; x < 15; ++x)
                        s[x] += __popc(aw[x + kw] ^ wk);
                }
            }
        #pragma unroll
        for (int p = 0; p < 7; ++p) {
            int m = min(min(s[2*p], s[2*p+1]), s[2*p+2]);
            smin[p] = min(smin[p], m);
        }
    }

    const int o = ot * 128 + ol;
    float scale = bnp[o] / sqrtf(bnp[768 + o] + EPS);
    float m = bnp[512 + o], be = bnp[256 + o];
    const int lane = threadIdx.x & 63;
    const int wv = threadIdx.x >> 6;
    const int cwbase = ot * 4 + (wv & 1) * 2;
    const int nvalid = 7 - xh;   // xh1: px 7..12 only
    #pragma unroll
    for (int p = 0; p < 7; ++p) {
        float dot = (float)(2400 - 2 * smin[p]);
        bool bit = (dot - m) * scale + be < 0.f;
        unsigned long long bal = __ballot(bit);
        if (p < nvalid) {
            int xp = xh * 7 + p + 1;
            if (lane == 0)
                pout[((size_t)(b * 8 + cwbase) * 15 + yp) * 15 + xp] = (uint32_t)bal;
            if (lane == 32)
                pout[((size_t)(b * 8 + cwbase + 1) * 15 + yp) * 15 + xp] = (uint32_t)(bal >> 32);
        }
    }
    if (threadIdx.x < 8) {
        int cw4 = threadIdx.x & 3, side = threadIdx.x >> 2;
        pout[((size_t)(b * 8 + ot * 4 + cw4) * 15 + yp) * 15 + (side ? 14 : 0)] = 0xFFFFFFFFu;
    }
}

// ---------------------------------------------------------------------------
// 3x3 binconv + bn + sign + pack pad1 (conv3, conv4).
// in [b][CW][15][15], w [O][CW*9], out [b][O/32][15][15]
// grid (15 yp, O/128 ot, 128 b), block 256
// ---------------------------------------------------------------------------
template <int CW>
__global__ __launch_bounds__(256) void binconv33_pack(
    const uint32_t* __restrict__ pa, const uint32_t* __restrict__ pw,
    uint32_t* __restrict__ pout, const float* __restrict__ bnp, int O)
{
    constexpr int KW = CW * 9;
    const int yp = blockIdx.x, ot = blockIdx.y, b = blockIdx.z;
    const int CWout = O >> 5;
    __shared__ uint32_t wl[KW * 129];
    __shared__ uint32_t al[CW * 45 + 24];
    if (yp == 0 || yp == 14) {
        for (int i = threadIdx.x; i < 60; i += 256) {
            int cw4 = i / 15, xp = i % 15;
            pout[((size_t)(b * CWout + ot * 4 + cw4) * 15 + yp) * 15 + xp] = 0xFFFFFFFFu;
        }
        return;
    }
    const int y = yp - 1;
    const uint32_t* pwb = pw + (size_t)(ot * 128) * KW;
    for (int idx = threadIdx.x; idx < 128 * KW; idx += 256) {
        int o = idx / KW, k = idx % KW;
        wl[k * 129 + o] = pwb[idx];
    }
    const uint32_t* pab = pa + (size_t)b * CW * 225;
    for (int idx = threadIdx.x; idx < CW * 45; idx += 256) {
        int cw = idx / 45, r = (idx / 15) % 3, xp = idx % 15;
        al[idx] = pab[(size_t)cw * 225 + (y + r) * 15 + xp];
    }
    __syncthreads();

    const int ol = threadIdx.x & 127;
    const int xh = threadIdx.x >> 7;
    const int xs = xh * 7;
    int acc[7] = {0,0,0,0,0,0,0};
    #pragma unroll
    for (int cw = 0; cw < CW; ++cw)
        #pragma unroll
        for (int kh = 0; kh < 3; ++kh) {
            uint32_t aw[9];
            #pragma unroll
            for (int j = 0; j < 9; ++j)
                aw[j] = al[(cw * 3 + kh) * 15 + xs + j];
            uint32_t w0 = wl[(cw * 9 + kh * 3 + 0) * 129 + ol];
            uint32_t w1 = wl[(cw * 9 + kh * 3 + 1) * 129 + ol];
            uint32_t w2 = wl[(cw * 9 + kh * 3 + 2) * 129 + ol];
            #pragma unroll
            for (int x = 0; x < 7; ++x)
                acc[x] += __popc(aw[x] ^ w0) + __popc(aw[x+1] ^ w1) + __popc(aw[x+2] ^ w2);
        }

    const int o = ot * 128 + ol;
    float scale = bnp[o] / sqrtf(bnp[3 * O + o] + EPS);
    float m = bnp[2 * O + o], be = bnp[O + o];
    const int lane = threadIdx.x & 63;
    const int wv = threadIdx.x >> 6;
    const int cwbase = ot * 4 + (wv & 1) * 2;
    const int nvalid = 7 - xh;
    #pragma unroll
    for (int x = 0; x < 7; ++x) {
        float dot = (float)(CW * 288 - 2 * acc[x]);
        bool bit = (dot - m) * scale + be < 0.f;
        unsigned long long bal = __ballot(bit);
        if (x < nvalid) {
            int xp = xs + x + 1;
            if (lane == 0)
                pout[((size_t)(b * CWout + cwbase) * 15 + yp) * 15 + xp] = (uint32_t)bal;
            if (lane == 32)
                pout[((size_t)(b * CWout + cwbase + 1) * 15 + yp) * 15 + xp] = (uint32_t)(bal >> 32);
        }
    }
    if (threadIdx.x < 8) {
        int cw4 = threadIdx.x & 3, side = threadIdx.x >> 2;
        pout[((size_t)(b * CWout + ot * 4 + cw4) * 15 + yp) * 15 + (side ? 14 : 0)] = 0xFFFFFFFFu;
    }
}

// ---------------------------------------------------------------------------
// binconv5 + maxpool(13->6) + bn5 + sign -> bytes [b][256][36]
// grid (6 py, 2 ot, 128 b), block 256
// ---------------------------------------------------------------------------
__global__ __launch_bounds__(256) void binconv5_pool(
    const uint32_t* __restrict__ pa, const uint32_t* __restrict__ pw,
    unsigned char* __restrict__ sout, const float* __restrict__ bnp)
{
    const int py = blockIdx.x, ot = blockIdx.y, b = blockIdx.z;
    __shared__ uint32_t wl[108 * 129];
    __shared__ uint32_t al[900 + 12];
    const uint32_t* pwb = pw + (size_t)(ot * 128) * 108;
    for (int idx = threadIdx.x; idx < 128 * 108; idx += 256) {
        int o = idx / 108, k = idx % 108;
        wl[k * 129 + o] = pwb[idx];
    }
    const uint32_t* pab = pa + (size_t)b * 12 * 225;
    for (int idx = threadIdx.x; idx < 900; idx += 256) {
        int cw = idx / 75, rr = (idx / 15) % 5, xp = idx % 15;
        al[idx] = pab[(size_t)cw * 225 + (2 * py + rr) * 15 + xp];
    }
    __syncthreads();

    const int ol = threadIdx.x & 127;
    const int xh = threadIdx.x >> 7;
    const int xs = xh * 6;
    int smin[3] = {INT_MAX, INT_MAX, INT_MAX};
    for (int r = 0; r < 3; ++r) {
        int s[7] = {0,0,0,0,0,0,0};
        #pragma unroll
        for (int cw = 0; cw < 12; ++cw)
            #pragma unroll
            for (int kh = 0; kh < 3; ++kh) {
                uint32_t aw[9];
                #pragma unroll
                for (int j = 0; j < 9; ++j)
                    aw[j] = al[cw * 75 + (r + kh) * 15 + xs + j];
                uint32_t w0 = wl[(cw * 9 + kh * 3 + 0) * 129 + ol];
                uint32_t w1 = wl[(cw * 9 + kh * 3 + 1) * 129 + ol];
                uint32_t w2 = wl[(cw * 9 + kh * 3 + 2) * 129 + ol];
                #pragma unroll
                for (int x = 0; x < 7; ++x)
                    s[x] += __popc(aw[x] ^ w0) + __popc(aw[x+1] ^ w1) + __popc(aw[x+2] ^ w2);
            }
        #pragma unroll
        for (int p = 0; p < 3; ++p)
            smin[p] = min(smin[p], min(min(s[2*p], s[2*p+1]), s[2*p+2]));
    }
    const int o = ot * 128 + ol;
    float scale = bnp[o] / sqrtf(bnp[768 + o] + EPS);
    float m = bnp[512 + o], be = bnp[256 + o];
    #pragma unroll
    for (int p = 0; p < 3; ++p) {
        float dot = (float)(3456 - 2 * smin[p]);
        bool bit = (dot - m) * scale + be < 0.f;
        sout[(size_t)(b * 256 + o) * 36 + py * 6 + xs / 2 + p] = bit ? 1 : 0;
    }
}

// S5 bytes [128][9216] -> packed words [128][288]
__global__ __launch_bounds__(256) void pack_s5(
    const unsigned char* __restrict__ s, uint32_t* __restrict__ out)
{
    int idx = blockIdx.x * 256 + threadIdx.x;
    if (idx >= 128 * 288) return;
    const uint32_t* p = (const uint32_t*)(s + (size_t)idx * 32);
    uint32_t word = 0;
    #pragma unroll
    for (int q = 0; q < 8; ++q) {
        uint32_t v = p[q];
        word |= ((v & 1u) | ((v >> 7) & 2u) | ((v >> 14) & 4u) | ((v >> 21) & 8u)) << (4 * q);
    }
    out[idx] = word;
}

// coalesced sign-pack of a flat fp32 array (count must be multiple of 2048)
__global__ __launch_bounds__(256) void packflat_fast(
    const float* __restrict__ in, uint32_t* __restrict__ out, int ntiles)
{
    int nw = (gridDim.x * 256) >> 6;
    int wid = (blockIdx.x * 256 + threadIdx.x) >> 6;
    int lane = threadIdx.x & 63;
    for (int t = wid; t < ntiles; t += nw) {
        size_t base = (size_t)t * 2048;
        #pragma unroll 4
        for (int c = 0; c < 32; ++c) {
            float v = in[base + (size_t)c * 64 + lane];
            unsigned long long bal = __ballot(v < 0.f);
            if (lane == 0)  out[(base >> 5) + 2 * c]     = (uint32_t)bal;
            if (lane == 32) out[(base >> 5) + 2 * c + 1] = (uint32_t)(bal >> 32);
        }
    }
}

// ---------------------------------------------------------------------------
// bingemm1: [128,288w] x [4096,288w] -> bn6 -> sign -> packed [128,128w]
// grid (16 ot, 16 bt), block 256
// ---------------------------------------------------------------------------
__global__ __launch_bounds__(256) void bingemm1_pack(
    const uint32_t* __restrict__ xp, const uint32_t* __restrict__ wp,
    uint32_t* __restrict__ pout, const float* __restrict__ bnp)
{
    const int ot = blockIdx.x, bt = blockIdx.y;
    __shared__ uint32_t xl[8 * 288];
    for (int i = threadIdx.x; i < 8 * 288; i += 256)
        xl[i] = xp[(size_t)(bt * 8 + i / 288) * 288 + (i % 288)];
    __syncthreads();
    const int o = ot * 256 + threadIdx.x;
    const uint32_t* wr = wp + (size_t)o * 288;
    int acc[8] = {0,0,0,0,0,0,0,0};
    for (int k = 0; k < 288; k += 4) {
        uint4 w4 = *(const uint4*)&wr[k];
        #pragma unroll
        for (int bb = 0; bb < 8; ++bb) {
            uint4 x4 = *(const uint4*)&xl[bb * 288 + k];
            acc[bb] += __popc(w4.x ^ x4.x) + __popc(w4.y ^ x4.y)
                     + __popc(w4.z ^ x4.z) + __popc(w4.w ^ x4.w);
        }
    }
    float scale = bnp[o] / sqrtf(bnp[3 * 4096 + o] + EPS);
    float m = bnp[2 * 4096 + o], be = bnp[4096 + o];
    const int lane = threadIdx.x & 63;
    const int wordbase = ot * 8 + (threadIdx.x >> 6) * 2;
    #pragma unroll
    for (int bb = 0; bb < 8; ++bb) {
        float dot = (float)(9216 - 2 * acc[bb]);
        bool bit = (dot - m) * scale + be < 0.f;
        unsigned long long bal = __ballot(bit);
        if (lane == 0)  pout[(size_t)(bt * 8 + bb) * 128 + wordbase]     = (uint32_t)bal;
        if (lane == 32) pout[(size_t)(bt * 8 + bb) * 128 + wordbase + 1] = (uint32_t)(bal >> 32);
    }
}

// ---------------------------------------------------------------------------
// bingemm2: [128,128w] x [4096,128w] -> bn7 -> relu -> f32 [128,4096]
// ---------------------------------------------------------------------------
__global__ __launch_bounds__(256) void bingemm2_relu(
    const uint32_t* __restrict__ xp, const uint32_t* __restrict__ wp,
    float* __restrict__ outp, const float* __restrict__ bnp)
{
    const int ot = blockIdx.x, bt = blockIdx.y;
    __shared__ uint32_t xl[8 * 128];
    for (int i = threadIdx.x; i < 8 * 128; i += 256)
        xl[i] = xp[(size_t)(bt * 8 + i / 128) * 128 + (i % 128)];
    __syncthreads();
    const int o = ot * 256 + threadIdx.x;
    const uint32_t* wr = wp + (size_t)o * 128;
    int acc[8] = {0,0,0,0,0,0,0,0};
    for (int k = 0; k < 128; k += 4) {
        uint4 w4 = *(const uint4*)&wr[k];
        #pragma unroll
        for (int bb = 0; bb < 8; ++bb) {
            uint4 x4 = *(const uint4*)&xl[bb * 128 + k];
            acc[bb] += __popc(w4.x ^ x4.x) + __popc(w4.y ^ x4.y)
                     + __popc(w4.z ^ x4.z) + __popc(w4.w ^ x4.w);
        }
    }
    float scale = bnp[o] / sqrtf(bnp[3 * 4096 + o] + EPS);
    float m = bnp[2 * 4096 + o], be = bnp[4096 + o];
    #pragma unroll
    for (int bb = 0; bb < 8; ++bb) {
        float dot = (float)(4096 - 2 * acc[bb]);
        float v = (dot - m) * scale + be;
        outp[(size_t)(bt * 8 + bb) * 4096 + o] = fmaxf(v, 0.f);
    }
}

// ---------------------------------------------------------------------------
// fc3: [128,4096] x [1000,4096]^T + bias, K-split 8
// ---------------------------------------------------------------------------
__global__ __launch_bounds__(256) void fc3_partial_kernel(
    const float* __restrict__ in, const float* __restrict__ w, float* __restrict__ part)
{
    const int otile = blockIdx.x * 64;
    const int kbase = blockIdx.y * 512;
    __shared__ float xs[32][132];
    __shared__ float wt[32][68];
    const int tid = threadIdx.x;
    const int ox = (tid & 15) * 4;
    const int bx = (tid >> 4) * 8;
    float acc[4][8];
    #pragma unroll
    for (int i = 0; i < 4; ++i)
        #pragma unroll
        for (int j = 0; j < 8; ++j) acc[i][j] = 0.f;

    for (int kc = 0; kc < 512; kc += 32) {
        __syncthreads();
        #pragma unroll
        for (int j = 0; j < 16; ++j) {
            int idx = tid + j * 256;
            int bb = idx >> 5, kk = idx & 31;
            xs[kk][bb] = in[(size_t)bb * 4096 + kbase + kc + kk];
        }
        #pragma unroll
        for (int j = 0; j < 8; ++j) {
            int idx = tid + j * 256;
            int oo = idx >> 5, kk = idx & 31;
            int og = otile + oo;
            wt[kk][oo] = (og < 1000) ? w[(size_t)og * 4096 + kbase + kc + kk] : 0.f;
        }
        __syncthreads();
        #pragma unroll
        for (int kk = 0; kk < 32; ++kk) {
            float4 wv = *(const float4*)&wt[kk][ox];
            float4 x0 = *(const float4*)&xs[kk][bx];
            float4 x1 = *(const float4*)&xs[kk][bx + 4];
            float wvv[4] = {wv.x, wv.y, wv.z, wv.w};
            float xv[8]  = {x0.x, x0.y, x0.z, x0.w, x1.x, x1.y, x1.z, x1.w};
            #pragma unroll
            for (int i = 0; i < 4; ++i)
                #pragma unroll
                for (int j = 0; j < 8; ++j)
                    acc[i][j] = fmaf(wvv[i], xv[j], acc[i][j]);
        }
    }
    float* pb = part + (size_t)blockIdx.y * 128 * 1024;
    #pragma unroll
    for (int i = 0; i < 4; ++i)
        #pragma unroll
        for (int j = 0; j < 8; ++j)
            pb[(size_t)(bx + j) * 1024 + otile + ox + i] = acc[i][j];
}

__global__ __launch_bounds__(256) void fc3_reduce_kernel(
    const float* __restrict__ part, const float* __restrict__ bias,
    float* __restrict__ out)
{
    int idx = blockIdx.x * 256 + threadIdx.x;
    if (idx >= 128 * 1000) return;
    int o = idx % 1000, b = idx / 1000;
    float s = bias[o];
    #pragma unroll
    for (int k = 0; k < 8; ++k)
        s += part[((size_t)k * 128 + b) * 1024 + o];
    out[idx] = s;
}

// ---------------------------------------------------------------------------
// launch
// ---------------------------------------------------------------------------
extern "C" void kernel_launch(void* const* d_in, const int* in_sizes, int n_in,
                              void* d_out, int out_size, void* d_ws, size_t ws_size,
                              hipStream_t stream)
{
    const float* x        = (const float*)d_in[0];
    const float* conv1_w  = (const float*)d_in[1];
    const float* bconv2_w = (const float*)d_in[2];
    const float* bconv3_w = (const float*)d_in[3];
    const float* bconv4_w = (const float*)d_in[4];
    const float* bconv5_w = (const float*)d_in[5];
    const float* blin1_w  = (const float*)d_in[6];
    const float* blin2_w  = (const float*)d_in[7];
    const float* lin3_w   = (const float*)d_in[8];
    const float* lin3_b   = (const float*)d_in[9];
    const float* bn1 = (const float*)d_in[10];
    const float* bn2 = (const float*)d_in[11];
    const float* bn3 = (const float*)d_in[12];
    const float* bn4 = (const float*)d_in[13];
    const float* bn5 = (const float*)d_in[14];
    const float* bn6 = (const float*)d_in[15];
    const float* bn7 = (const float*)d_in[16];
    float* out = (float*)d_out;

    // workspace layout (bytes, 256-aligned)
    char* ws = (char*)d_ws;
    float*         A    = (float*)(ws + 0);                 // 148,684,800
    uint32_t*      PB1  = (uint32_t*)(ws + 148684800);      //  1,572,864
    uint32_t*      PB2  = (uint32_t*)(ws + 150257664);      //  1,572,864
    uint32_t*      PW   = (uint32_t*)(ws + 151830528);      //    196,608
    unsigned char* S5   = (unsigned char*)(ws + 152027136); //  1,179,648
    uint32_t*      PFC1 = (uint32_t*)(ws + 153206784);      //    147,456
    uint32_t*      PFC2 = (uint32_t*)(ws + 153354240);      //     65,536
    uint32_t*      PWF1 = (uint32_t*)(ws + 153419776);      //  4,718,592
    uint32_t*      PWF2 = (uint32_t*)(ws + 158138368);      //  2,097,152
    float*         FC2  = (float*)(ws + 160235520);         //  2,097,152
    float*         PART = (float*)(ws + 162332672);         //  4,194,304
    __bf16*        WTH  = (__bf16*)(ws + 166526976);        //    102,400
    __bf16*        WTL  = (__bf16*)(ws + 166629376);        //    102,400

    // conv1
    conv1_wprep<<<(96 * 33 * 16 + 255) / 256, 256, 0, stream>>>(conv1_w, WTH, WTL);
    conv1_mfma<<<dim3(55, 128), 384, 0, stream>>>(x, WTH, WTL, A);

    // stage1: pool+bn1+sign+pack(pad2) -> PB1 [128,3,31,31]
    poolpack1<<<(128 * 3 * 31 * 31 + 255) / 256, 256, 0, stream>>>(A, PB1, bn1);

    // conv2 (fused pool+bn2+pack) -> PB2 [128,8,15,15]
    packw_kernel<<<(256 * 3 * 25 + 255) / 256, 256, 0, stream>>>(bconv2_w, PW, 96, 25, 256 * 3 * 25);
    binconv2_pool<<<dim3(15, 2, 128), 256, 0, stream>>>(PB1, PW, PB2, bn2);

    // conv3 (+bn3+pack) -> PB1 [128,12,15,15]
    packw_kernel<<<(384 * 8 * 9 + 255) / 256, 256, 0, stream>>>(bconv3_w, PW, 256, 9, 384 * 8 * 9);
    binconv33_pack<8><<<dim3(15, 3, 128), 256, 0, stream>>>(PB2, PW, PB1, bn3, 384);

    // conv4 (+bn4+pack) -> PB2 [128,12,15,15]
    packw_kernel<<<(384 * 12 * 9 + 255) / 256, 256, 0, stream>>>(bconv4_w, PW, 384, 9, 384 * 12 * 9);
    binconv33_pack<12><<<dim3(15, 3, 128), 256, 0, stream>>>(PB1, PW, PB2, bn4, 384);

    // conv5 (fused pool+bn5+sign) -> S5 bytes, then pack -> PFC1 [128,288]
    packw_kernel<<<(256 * 12 * 9 + 255) / 256, 256, 0, stream>>>(bconv5_w, PW, 384, 9, 256 * 12 * 9);
    binconv5_pool<<<dim3(6, 2, 128), 256, 0, stream>>>(PB2, PW, S5, bn5);
    pack_s5<<<(128 * 288 + 255) / 256, 256, 0, stream>>>(S5, PFC1);

    // fc weights pack
    packflat_fast<<<512, 256, 0, stream>>>(blin1_w, PWF1, 18432);
    // bingemm1 + bn6 + sign -> PFC2 [128,128]
    bingemm1_pack<<<dim3(16, 16), 256, 0, stream>>>(PFC1, PWF1, PFC2, bn6);

    packflat_fast<<<512, 256, 0, stream>>>(blin2_w, PWF2, 8192);
    // bingemm2 + bn7 + relu -> FC2 [128,4096]
    bingemm2_relu<<<dim3(16, 16), 256, 0, stream>>>(PFC2, PWF2, FC2, bn7);

    // fc3
    fc3_partial_kernel<<<dim3(16, 8), 256, 0, stream>>>(FC2, lin3_w, PART);
    fc3_reduce_kernel<<<(128 * 1000 + 255) / 256, 256, 0, stream>>>(PART, lin3_b, out);
}